// Round 1
// baseline (33375.714 us; speedup 1.0000x reference)
//
#include <hip/hip_runtime.h>

// CustomLSTM  B=32, T=2048, H=512  (fp32 in/out)
// Fused persistent kernel: 32 WGs, each owns 16 hidden columns (all 4 gates).
// U,V weight slices live in VGPRs (bf16 frags) for all 2048 steps.
// Per step: gates = x_t*U (precomputed 1 step ahead) + h_{t-1}*V via MFMA,
// elementwise LSTM cell, h exchanged through device-coherent ws buffers,
// monotonic atomic-counter barrier across the 32 WGs.

#define BB 32
#define TT 2048
#define HH 512
#define NWG 32
#define HS (BB*TT*HH)   // hidden_seq element count = 33554432

typedef short short8 __attribute__((ext_vector_type(8)));
typedef float floatx4 __attribute__((ext_vector_type(4)));

__device__ __forceinline__ unsigned short f2bf(float f) {
  union { float f; unsigned u; } v; v.f = f;
  return (unsigned short)((v.u + 0x7FFFu + ((v.u >> 16) & 1u)) >> 16);
}
__device__ __forceinline__ float sigm(float z) { return 1.0f / (1.0f + __expf(-z)); }
__device__ __forceinline__ float tanh_fast(float z) { return 1.0f - 2.0f / (__expf(2.0f * z) + 1.0f); }

__global__ __launch_bounds__(512, 2)
void lstm_kernel(const float* __restrict__ x,
                 const float* __restrict__ Ui, const float* __restrict__ Vi, const float* __restrict__ bi,
                 const float* __restrict__ Uf, const float* __restrict__ Vf, const float* __restrict__ bf,
                 const float* __restrict__ Uc, const float* __restrict__ Vc, const float* __restrict__ bc,
                 const float* __restrict__ Uo, const float* __restrict__ Vo, const float* __restrict__ bo,
                 float* __restrict__ out,
                 unsigned short* __restrict__ hbuf,   // 2 x [32][512] bf16 double buffer (in ws, zeroed)
                 unsigned* __restrict__ count)        // barrier counter (in ws, zeroed)
{
  __shared__ float gates[4][BB][16];   // [gate][batch][j-local] pre-activations (8 KB)

  const int tid  = threadIdx.x;
  const int wg   = blockIdx.x;         // 0..31 -> hidden column slice
  const int lane = tid & 63;
  const int wid  = tid >> 6;           // 0..7
  const int mt   = wid & 1;            // batch half (16 rows)
  const int gt   = wid >> 1;           // gate 0..3 (i,f,c,o)
  const int j0   = wg * 16;
  const int ln   = lane & 15;
  const int kh   = (lane >> 4) * 8;    // k-offset of this lane's 8 A/B elements
  const int brow = mt * 16 + ln;       // batch row for A fragments

  const float* Ug = (gt == 0) ? Ui : (gt == 1) ? Uf : (gt == 2) ? Uc : Uo;
  const float* Vg = (gt == 0) ? Vi : (gt == 1) ? Vf : (gt == 2) ? Vc : Vo;

  // ---- prologue: load persistent bf16 weight fragments (column j0+ln of Ug/Vg) ----
  short8 ufr[16], vfr[16];
#pragma unroll
  for (int kc = 0; kc < 16; ++kc) {
    short8 a, b;
#pragma unroll
    for (int i = 0; i < 8; ++i) {
      const int krow = kc * 32 + kh + i;
      a[i] = (short)f2bf(Ug[(size_t)krow * HH + j0 + ln]);
      b[i] = (short)f2bf(Vg[(size_t)krow * HH + j0 + ln]);
    }
    ufr[kc] = a; vfr[kc] = b;
  }

  // elementwise-phase thread mapping: tid<256 -> (batch eb, column pair ej)
  float bia[4][2];
  float c0 = 0.f, c1 = 0.f;
  int eb = 0, ej = 0;
  if (tid < 256) {
    eb = tid >> 3; ej = (tid & 7) * 2;
    bia[0][0] = bi[j0 + ej]; bia[0][1] = bi[j0 + ej + 1];
    bia[1][0] = bf[j0 + ej]; bia[1][1] = bf[j0 + ej + 1];
    bia[2][0] = bc[j0 + ej]; bia[2][1] = bc[j0 + ej + 1];
    bia[3][0] = bo[j0 + ej]; bia[3][1] = bo[j0 + ej + 1];
  }

  // ---- x*U part for t=0 ----
  floatx4 accn = {0.f, 0.f, 0.f, 0.f};
  {
    const float* px = x + (size_t)brow * TT * HH;   // t = 0
#pragma unroll
    for (int kc = 0; kc < 16; ++kc) {
      short8 xa;
#pragma unroll
      for (int i = 0; i < 8; ++i) xa[i] = (short)f2bf(px[kc * 32 + kh + i]);
      accn = __builtin_amdgcn_mfma_f32_16x16x32_bf16(xa, ufr[kc], accn, 0, 0, 0);
    }
  }

  for (int t = 0; t < TT; ++t) {
    // ---- wait for h[t-1] from all WGs ----
    if (t > 0) {
      if (tid == 0) {
        const unsigned target = (unsigned)(NWG * t);
        while (__hip_atomic_load(count, __ATOMIC_RELAXED, __HIP_MEMORY_SCOPE_AGENT) < target) { }
      }
      __syncthreads();
    }

    // ---- gates += h[t-1] * V  (coherent bf16 loads bypass stale L1/L2) ----
    floatx4 acc = accn;
    {
      const unsigned short* hr = hbuf + (size_t)((t & 1) ^ 1) * (BB * HH);
#pragma unroll
      for (int kc = 0; kc < 16; ++kc) {
        union { unsigned long long q[2]; short8 s; } u;
        const unsigned long long* hp =
            (const unsigned long long*)(hr + (size_t)brow * HH + kc * 32 + kh);
        u.q[0] = __hip_atomic_load(hp,     __ATOMIC_RELAXED, __HIP_MEMORY_SCOPE_AGENT);
        u.q[1] = __hip_atomic_load(hp + 1, __ATOMIC_RELAXED, __HIP_MEMORY_SCOPE_AGENT);
        acc = __builtin_amdgcn_mfma_f32_16x16x32_bf16(u.s, vfr[kc], acc, 0, 0, 0);
      }
    }

    // ---- D-frag -> gates LDS:  col = lane&15, row = (lane>>4)*4 + r ----
#pragma unroll
    for (int r = 0; r < 4; ++r)
      gates[gt][mt * 16 + (lane >> 4) * 4 + r][ln] = acc[r];

    // ---- overlap: x*U for step t+1 (independent of h) ----
    if (t < TT - 1) {
      floatx4 an = {0.f, 0.f, 0.f, 0.f};
      const float* px = x + ((size_t)brow * TT + (t + 1)) * HH;
#pragma unroll
      for (int kc = 0; kc < 16; ++kc) {
        short8 xa;
#pragma unroll
        for (int i = 0; i < 8; ++i) xa[i] = (short)f2bf(px[kc * 32 + kh + i]);
        an = __builtin_amdgcn_mfma_f32_16x16x32_bf16(xa, ufr[kc], an, 0, 0, 0);
      }
      accn = an;
    }

    __syncthreads();   // gates ready

    // ---- elementwise LSTM cell (256 threads: 32 batches x 8 column-pairs) ----
    if (tid < 256) {
      const float z00 = gates[0][eb][ej]     + bia[0][0];
      const float z01 = gates[0][eb][ej + 1] + bia[0][1];
      const float z10 = gates[1][eb][ej]     + bia[1][0];
      const float z11 = gates[1][eb][ej + 1] + bia[1][1];
      const float z20 = gates[2][eb][ej]     + bia[2][0];
      const float z21 = gates[2][eb][ej + 1] + bia[2][1];
      const float z30 = gates[3][eb][ej]     + bia[3][0];
      const float z31 = gates[3][eb][ej + 1] + bia[3][1];
      const float i0 = sigm(z00), i1 = sigm(z01);
      const float f0 = sigm(z10), f1 = sigm(z11);
      const float g0 = tanh_fast(z20), g1 = tanh_fast(z21);
      const float o0 = sigm(z30), o1 = sigm(z31);
      c0 = f0 * c0 + i0 * g0;
      c1 = f1 * c1 + i1 * g1;
      const float h0 = o0 * tanh_fast(c0);
      const float h1 = o1 * tanh_fast(c1);

      // hidden_seq (fp32, pre-rounding)
      float2 hv = make_float2(h0, h1);
      *(float2*)(out + ((size_t)eb * TT + t) * HH + j0 + ej) = hv;

      // h for next step: packed bf16, device-coherent store
      const unsigned pk = (unsigned)f2bf(h0) | ((unsigned)f2bf(h1) << 16);
      unsigned* hw = (unsigned*)(hbuf + (size_t)(t & 1) * (BB * HH));
      __hip_atomic_store(hw + ((eb * HH + j0 + ej) >> 1), pk,
                         __ATOMIC_RELAXED, __HIP_MEMORY_SCOPE_AGENT);

      if (t == TT - 1) {
        out[(size_t)HS + eb * HH + j0 + ej]              = h0;
        out[(size_t)HS + eb * HH + j0 + ej + 1]          = h1;
        out[(size_t)HS + BB * HH + eb * HH + j0 + ej]     = c0;
        out[(size_t)HS + BB * HH + eb * HH + j0 + ej + 1] = c1;
      }
    }

    __syncthreads();   // drains all waves' h stores (vmcnt) before arrival
    if (tid == 0)
      __hip_atomic_fetch_add(count, 1u, __ATOMIC_RELEASE, __HIP_MEMORY_SCOPE_AGENT);
  }
}

extern "C" void kernel_launch(void* const* d_in, const int* in_sizes, int n_in,
                              void* d_out, int out_size, void* d_ws, size_t ws_size,
                              hipStream_t stream) {
  (void)in_sizes; (void)n_in; (void)out_size; (void)ws_size;
  const float* x  = (const float*)d_in[0];
  const float* Ui = (const float*)d_in[1];
  const float* Vi = (const float*)d_in[2];
  const float* bi = (const float*)d_in[3];
  const float* Uf = (const float*)d_in[4];
  const float* Vf = (const float*)d_in[5];
  const float* bf = (const float*)d_in[6];
  const float* Uc = (const float*)d_in[7];
  const float* Vc = (const float*)d_in[8];
  const float* bc = (const float*)d_in[9];
  const float* Uo = (const float*)d_in[10];
  const float* Vo = (const float*)d_in[11];
  const float* bo = (const float*)d_in[12];

  unsigned short* hbuf = (unsigned short*)d_ws;                    // 2 * 32KB bf16 h double-buffer
  unsigned* count = (unsigned*)((char*)d_ws + 2 * BB * HH * 2);    // +65536: barrier counter

  // reset h buffers + barrier counter every launch (graph-capture safe)
  hipMemsetAsync(d_ws, 0, 2 * BB * HH * 2 + 64, stream);

  lstm_kernel<<<dim3(NWG), dim3(512), 0, stream>>>(
      x, Ui, Vi, bi, Uf, Vf, bf, Uc, Vc, bc, Uo, Vo, bo,
      (float*)d_out, hbuf, count);
}

// Round 2
// 15395.441 us; speedup vs baseline: 2.1679x; 2.1679x over previous
//
#include <hip/hip_runtime.h>

// CustomLSTM  B=32, T=2048, H=512  (fp32 in/out)
// 32 persistent WGs, each owns 16 hidden columns (all 4 gates), weights in VGPRs.
// Coalesced everywhere: x staged via swizzled LDS, h exchanged in MFMA-fragment
// order through device-coherent ws, per-WG padded arrival flags for the barrier.

#define BB 32
#define TT 2048
#define HH 512
#define NWG 32
#define HS (BB*TT*HH)   // hidden_seq element count

typedef short short8 __attribute__((ext_vector_type(8)));
typedef float floatx4 __attribute__((ext_vector_type(4)));

__device__ __forceinline__ unsigned short f2bf(float f) {
  union { float f; unsigned u; } v; v.f = f;
  return (unsigned short)((v.u + 0x7FFFu + ((v.u >> 16) & 1u)) >> 16);
}
__device__ __forceinline__ unsigned pk2(float a, float b) {
  return (unsigned)f2bf(a) | ((unsigned)f2bf(b) << 16);
}
__device__ __forceinline__ float sigm(float z) { return 1.0f / (1.0f + __expf(-z)); }
__device__ __forceinline__ float tanh_fast(float z) { return 1.0f - 2.0f / (__expf(2.0f * z) + 1.0f); }

__global__ __launch_bounds__(512, 2)
void lstm_kernel(const float* __restrict__ x,
                 const float* __restrict__ Ui, const float* __restrict__ Vi, const float* __restrict__ bi,
                 const float* __restrict__ Uf, const float* __restrict__ Vf, const float* __restrict__ bf,
                 const float* __restrict__ Uc, const float* __restrict__ Vc, const float* __restrict__ bc,
                 const float* __restrict__ Uo, const float* __restrict__ Vo, const float* __restrict__ bo,
                 float* __restrict__ out,
                 unsigned long long* __restrict__ hbuf,  // 2 x 4096 x 8B, h in frag order (ws, zeroed)
                 unsigned* __restrict__ flags)           // 32 x 64B arrival flags (ws, zeroed)
{
  __shared__ __align__(16) unsigned char lds_x[BB * HH * 2];  // x_{t+1} bf16, swizzled [32][512]
  __shared__ __align__(16) float gates[4][BB][20];            // stride 20: conflict-free

  const int tid  = threadIdx.x;
  const int wg   = blockIdx.x;         // hidden column slice
  const int lane = tid & 63;
  const int wid  = tid >> 6;           // 0..7
  const int mt   = wid & 1;            // batch half
  const int gt   = wid >> 1;           // gate 0..3
  const int j0   = wg * 16;
  const int ln   = lane & 15;
  const int brow = mt * 16 + ln;

  // x-frag LDS addressing: A[row=brow][k=kc*32+(lane>>4)*8 + i]
  const int xfbase = brow * 1024 + ((lane >> 4) * 16);
  const int xfswz  = (brow & 7) << 4;
  // h-frag (global, frag-order): ull index = kc*256 + (mt*64+lane)*2
  const int hfbase = (mt * 64 + lane) * 2;

  // x staging mapping: 512 thr x 8 rounds x float4; round r covers batch rows 4r..4r+3
  const int bb0 = tid >> 7;            // 0..3
  const int kk  = (tid & 127) * 4;     // col within row

  const float* Ug = (gt == 0) ? Ui : (gt == 1) ? Uf : (gt == 2) ? Uc : Uo;
  const float* Vg = (gt == 0) ? Vi : (gt == 1) ? Vf : (gt == 2) ? Vc : Vo;

  // ---- prologue: persistent bf16 weight fragments (one-time, uncoalesced ok) ----
  short8 ufr[16], vfr[16];
#pragma unroll
  for (int kc = 0; kc < 16; ++kc) {
    short8 a, b;
#pragma unroll
    for (int i = 0; i < 8; ++i) {
      const int krow = kc * 32 + (lane >> 4) * 8 + i;
      a[i] = (short)f2bf(Ug[(size_t)krow * HH + j0 + ln]);
      b[i] = (short)f2bf(Vg[(size_t)krow * HH + j0 + ln]);
    }
    ufr[kc] = a; vfr[kc] = b;
  }

  // elementwise mapping + biases
  float bia[4][2];
  float c0 = 0.f, c1 = 0.f;
  int eb = 0, ej = 0;
  if (tid < 256) {
    eb = tid >> 3; ej = (tid & 7) * 2;
    bia[0][0] = bi[j0 + ej]; bia[0][1] = bi[j0 + ej + 1];
    bia[1][0] = bf[j0 + ej]; bia[1][1] = bf[j0 + ej + 1];
    bia[2][0] = bc[j0 + ej]; bia[2][1] = bc[j0 + ej + 1];
    bia[3][0] = bo[j0 + ej]; bia[3][1] = bo[j0 + ej + 1];
  }

  // ---- stage x(0) -> LDS, compute accn = x0*U ----
  float4 xr[8];
#pragma unroll
  for (int r = 0; r < 8; ++r) {
    const int b = r * 4 + bb0;
    xr[r] = *(const float4*)(x + (size_t)b * TT * HH + kk);
  }
#pragma unroll
  for (int r = 0; r < 8; ++r) {
    const int b = r * 4 + bb0;
    const int byte = b * 1024 + kk * 2;
    uint2 p; p.x = pk2(xr[r].x, xr[r].y); p.y = pk2(xr[r].z, xr[r].w);
    *(uint2*)(lds_x + (byte ^ ((b & 7) << 4))) = p;
  }
  __syncthreads();
  floatx4 accn = {0.f, 0.f, 0.f, 0.f};
#pragma unroll
  for (int kc = 0; kc < 16; ++kc) {
    const short8 xf = *(const short8*)(lds_x + ((xfbase + kc * 64) ^ xfswz));
    accn = __builtin_amdgcn_mfma_f32_16x16x32_bf16(xf, ufr[kc], accn, 0, 0, 0);
  }
  __syncthreads();   // protect lds_x before loop restage

  for (int t = 0; t < TT; ++t) {
    // ---- pre-issue x(t+1) loads (latency hides under the barrier poll) ----
    if (t + 1 < TT) {
#pragma unroll
      for (int r = 0; r < 8; ++r) {
        const int b = r * 4 + bb0;
        xr[r] = *(const float4*)(x + ((size_t)b * TT + (t + 1)) * HH + kk);
      }
    }

    // ---- wait for h[t-1] from all WGs ----
    if (t > 0) {
      if (tid < NWG) {
        while (__hip_atomic_load(&flags[tid * 16], __ATOMIC_RELAXED,
                                 __HIP_MEMORY_SCOPE_AGENT) < (unsigned)t) { }
      }
      __syncthreads();   // A
    }

    // ---- gates = accn + h[t-1]*V  (coalesced coherent frag loads) ----
    floatx4 acc = accn;
    {
      unsigned long long* hr = hbuf + (size_t)((t & 1) ^ 1) * 4096;
#pragma unroll
      for (int kc = 0; kc < 16; ++kc) {
        union { unsigned long long q[2]; short8 s; } u;
        u.q[0] = __hip_atomic_load(hr + hfbase + kc * 256,     __ATOMIC_RELAXED, __HIP_MEMORY_SCOPE_AGENT);
        u.q[1] = __hip_atomic_load(hr + hfbase + kc * 256 + 1, __ATOMIC_RELAXED, __HIP_MEMORY_SCOPE_AGENT);
        acc = __builtin_amdgcn_mfma_f32_16x16x32_bf16(u.s, vfr[kc], acc, 0, 0, 0);
      }
    }

    // ---- stage x(t+1): cvt + swizzled LDS write (overlaps MFMA latency) ----
    if (t + 1 < TT) {
#pragma unroll
      for (int r = 0; r < 8; ++r) {
        const int b = r * 4 + bb0;
        const int byte = b * 1024 + kk * 2;
        uint2 p; p.x = pk2(xr[r].x, xr[r].y); p.y = pk2(xr[r].z, xr[r].w);
        *(uint2*)(lds_x + (byte ^ ((b & 7) << 4))) = p;
      }
    }

    // ---- D-frag -> gates LDS ----
#pragma unroll
    for (int r = 0; r < 4; ++r)
      gates[gt][mt * 16 + (lane >> 4) * 4 + r][ln] = acc[r];

    __syncthreads();   // B: gates ready, x staged

    // ---- elementwise LSTM cell ----
    if (tid < 256) {
      const float z00 = gates[0][eb][ej]     + bia[0][0];
      const float z01 = gates[0][eb][ej + 1] + bia[0][1];
      const float z10 = gates[1][eb][ej]     + bia[1][0];
      const float z11 = gates[1][eb][ej + 1] + bia[1][1];
      const float z20 = gates[2][eb][ej]     + bia[2][0];
      const float z21 = gates[2][eb][ej + 1] + bia[2][1];
      const float z30 = gates[3][eb][ej]     + bia[3][0];
      const float z31 = gates[3][eb][ej + 1] + bia[3][1];
      const float i0 = sigm(z00), i1 = sigm(z01);
      const float f0 = sigm(z10), f1 = sigm(z11);
      const float g0 = tanh_fast(z20), g1 = tanh_fast(z21);
      const float o0 = sigm(z30), o1 = sigm(z31);
      c0 = f0 * c0 + i0 * g0;
      c1 = f1 * c1 + i1 * g1;
      const float h0 = o0 * tanh_fast(c0);
      const float h1 = o1 * tanh_fast(c1);

      *(float2*)(out + ((size_t)eb * TT + t) * HH + j0 + ej) = make_float2(h0, h1);

      // h store in frag order: row=eb, col=j0+ej
      const int col = j0 + ej;
      const int kc = col >> 5, hi = (col >> 3) & 3, ii = col & 7;
      const int F  = (kc * 2 + (eb >> 4)) * 64 + hi * 16 + (eb & 15);
      unsigned* hw = (unsigned*)(hbuf + (size_t)(t & 1) * 4096);
      __hip_atomic_store(hw + F * 4 + (ii >> 1), pk2(h0, h1),
                         __ATOMIC_RELAXED, __HIP_MEMORY_SCOPE_AGENT);

      if (t == TT - 1) {
        out[(size_t)HS + eb * HH + j0 + ej]               = h0;
        out[(size_t)HS + eb * HH + j0 + ej + 1]           = h1;
        out[(size_t)HS + BB * HH + eb * HH + j0 + ej]     = c0;
        out[(size_t)HS + BB * HH + eb * HH + j0 + ej + 1] = c1;
      }
    }

    // ---- accn = x(t+1)*U from LDS (overlaps elementwise) ----
    if (t + 1 < TT) {
      floatx4 an = {0.f, 0.f, 0.f, 0.f};
#pragma unroll
      for (int kc = 0; kc < 16; ++kc) {
        const short8 xf = *(const short8*)(lds_x + ((xfbase + kc * 64) ^ xfswz));
        an = __builtin_amdgcn_mfma_f32_16x16x32_bf16(xf, ufr[kc], an, 0, 0, 0);
      }
      accn = an;
    }

    __syncthreads();   // C: h stores drained (vmcnt), lds_x reads done

    if (tid == 0 && t + 1 < TT)
      __hip_atomic_store(&flags[wg * 16], (unsigned)(t + 1),
                         __ATOMIC_RELEASE, __HIP_MEMORY_SCOPE_AGENT);
  }
}

extern "C" void kernel_launch(void* const* d_in, const int* in_sizes, int n_in,
                              void* d_out, int out_size, void* d_ws, size_t ws_size,
                              hipStream_t stream) {
  (void)in_sizes; (void)n_in; (void)out_size; (void)ws_size;
  const float* x  = (const float*)d_in[0];
  const float* Ui = (const float*)d_in[1];
  const float* Vi = (const float*)d_in[2];
  const float* bi = (const float*)d_in[3];
  const float* Uf = (const float*)d_in[4];
  const float* Vf = (const float*)d_in[5];
  const float* bf = (const float*)d_in[6];
  const float* Uc = (const float*)d_in[7];
  const float* Vc = (const float*)d_in[8];
  const float* bc = (const float*)d_in[9];
  const float* Uo = (const float*)d_in[10];
  const float* Vo = (const float*)d_in[11];
  const float* bo = (const float*)d_in[12];

  unsigned long long* hbuf = (unsigned long long*)d_ws;          // 2 x 32KB frag-order h
  unsigned* flags = (unsigned*)((char*)d_ws + 65536);            // 32 x 64B flags

  hipMemsetAsync(d_ws, 0, 65536 + 2048, stream);

  lstm_kernel<<<dim3(NWG), dim3(512), 0, stream>>>(
      x, Ui, Vi, bi, Uf, Vf, bf, Uc, Vc, bc, Uo, Vo, bo,
      (float*)d_out, hbuf, flags);
}

// Round 3
// 13490.092 us; speedup vs baseline: 2.4741x; 1.1412x over previous
//
#include <hip/hip_runtime.h>

// CustomLSTM  B=32, T=2048, H=512  (fp32 in/out)
// 32 persistent WGs, each owns 16 hidden columns (all 4 gates), weights in VGPRs.
// h exchanged in MFMA-fragment order through LLC (relaxed sc1 atomics);
// per-step inter-WG barrier via packed relaxed flags (no L2 writeback).

#define BB 32
#define TT 2048
#define HH 512
#define NWG 32
#define HS (BB*TT*HH)   // hidden_seq element count

typedef short short8 __attribute__((ext_vector_type(8)));
typedef float floatx4 __attribute__((ext_vector_type(4)));

__device__ __forceinline__ unsigned short f2bf(float f) {
  union { float f; unsigned u; } v; v.f = f;
  return (unsigned short)((v.u + 0x7FFFu + ((v.u >> 16) & 1u)) >> 16);
}
__device__ __forceinline__ unsigned pk2(float a, float b) {
  return (unsigned)f2bf(a) | ((unsigned)f2bf(b) << 16);
}
__device__ __forceinline__ float sigm(float z) { return 1.0f / (1.0f + __expf(-z)); }
__device__ __forceinline__ float tanh_fast(float z) { return 1.0f - 2.0f / (__expf(2.0f * z) + 1.0f); }

__global__ __launch_bounds__(512, 2)
void lstm_kernel(const float* __restrict__ x,
                 const float* __restrict__ Ui, const float* __restrict__ Vi, const float* __restrict__ bi,
                 const float* __restrict__ Uf, const float* __restrict__ Vf, const float* __restrict__ bf,
                 const float* __restrict__ Uc, const float* __restrict__ Vc, const float* __restrict__ bc,
                 const float* __restrict__ Uo, const float* __restrict__ Vo, const float* __restrict__ bo,
                 float* __restrict__ out,
                 unsigned long long* __restrict__ hbuf,  // 2 x 4096 x 8B, h in frag order (ws, zeroed)
                 unsigned* __restrict__ flags)           // 32 packed arrival flags (ws, zeroed)
{
  __shared__ __align__(16) unsigned char lds_x[BB * HH * 2];  // x_{t+1} bf16, swizzled [32][512]
  __shared__ __align__(16) float gates[4][BB][21];            // odd stride: spread banks

  const int tid  = threadIdx.x;
  const int wg   = blockIdx.x;         // hidden column slice
  const int lane = tid & 63;
  const int wid  = tid >> 6;           // 0..7
  const int mt   = wid & 1;            // batch half
  const int gt   = wid >> 1;           // gate 0..3
  const int j0   = wg * 16;
  const int ln   = lane & 15;
  const int brow = mt * 16 + ln;

  // x-frag LDS addressing: A[row=brow][k=kc*32+(lane>>4)*8 + i]
  const int xfbase = brow * 1024 + ((lane >> 4) * 16);
  const int xfswz  = (brow & 7) << 4;
  // h-frag (global, frag-order): ull index = kc*256 + (mt*64+lane)*2
  const int hfbase = (mt * 64 + lane) * 2;

  // x staging mapping: 512 thr x 8 rounds x float4
  const int bb0 = tid >> 7;            // 0..3
  const int kk  = (tid & 127) * 4;     // col within row

  const float* Ug = (gt == 0) ? Ui : (gt == 1) ? Uf : (gt == 2) ? Uc : Uo;
  const float* Vg = (gt == 0) ? Vi : (gt == 1) ? Vf : (gt == 2) ? Vc : Vo;

  // ---- prologue: persistent bf16 weight fragments (one-time) ----
  short8 ufr[16], vfr[16];
#pragma unroll
  for (int kc = 0; kc < 16; ++kc) {
    short8 a, b;
#pragma unroll
    for (int i = 0; i < 8; ++i) {
      const int krow = kc * 32 + (lane >> 4) * 8 + i;
      a[i] = (short)f2bf(Ug[(size_t)krow * HH + j0 + ln]);
      b[i] = (short)f2bf(Vg[(size_t)krow * HH + j0 + ln]);
    }
    ufr[kc] = a; vfr[kc] = b;
  }

  // elementwise mapping + biases
  float bia[4][2];
  float c0 = 0.f, c1 = 0.f;
  int eb = 0, ej = 0;
  if (tid < 256) {
    eb = tid >> 3; ej = (tid & 7) * 2;
    bia[0][0] = bi[j0 + ej]; bia[0][1] = bi[j0 + ej + 1];
    bia[1][0] = bf[j0 + ej]; bia[1][1] = bf[j0 + ej + 1];
    bia[2][0] = bc[j0 + ej]; bia[2][1] = bc[j0 + ej + 1];
    bia[3][0] = bo[j0 + ej]; bia[3][1] = bo[j0 + ej + 1];
  }

  // ---- stage x(0) -> LDS, compute accn = x0*U ----
  float4 xr[8];
#pragma unroll
  for (int r = 0; r < 8; ++r) {
    const int b = r * 4 + bb0;
    xr[r] = *(const float4*)(x + (size_t)b * TT * HH + kk);
  }
#pragma unroll
  for (int r = 0; r < 8; ++r) {
    const int b = r * 4 + bb0;
    const int byte = b * 1024 + kk * 2;
    uint2 p; p.x = pk2(xr[r].x, xr[r].y); p.y = pk2(xr[r].z, xr[r].w);
    *(uint2*)(lds_x + (byte ^ ((b & 7) << 4))) = p;
  }
  __syncthreads();
  floatx4 accn = {0.f, 0.f, 0.f, 0.f};
#pragma unroll
  for (int kc = 0; kc < 16; ++kc) {
    const short8 xf = *(const short8*)(lds_x + ((xfbase + kc * 64) ^ xfswz));
    accn = __builtin_amdgcn_mfma_f32_16x16x32_bf16(xf, ufr[kc], accn, 0, 0, 0);
  }
  __syncthreads();   // protect lds_x before loop restage

  for (int t = 0; t < TT; ++t) {
    // ---- pre-issue x(t+1) loads (latency hides under the barrier poll) ----
    if (t + 1 < TT) {
#pragma unroll
      for (int r = 0; r < 8; ++r) {
        const int b = r * 4 + bb0;
        xr[r] = *(const float4*)(x + ((size_t)b * TT + (t + 1)) * HH + kk);
      }
    }

    // ---- wait for h[t-1] from all WGs (packed flags: 1 line) ----
    if (t > 0) {
      if (tid < NWG) {
        while (__hip_atomic_load(&flags[tid], __ATOMIC_RELAXED,
                                 __HIP_MEMORY_SCOPE_AGENT) < (unsigned)t) { }
      }
      __syncthreads();   // A
    }

    // ---- gates = accn + h[t-1]*V  (coalesced LLC frag loads) ----
    floatx4 acc = accn;
    {
      unsigned long long* hr = hbuf + (size_t)((t & 1) ^ 1) * 4096;
#pragma unroll
      for (int kc = 0; kc < 16; ++kc) {
        union { unsigned long long q[2]; short8 s; } u;
        u.q[0] = __hip_atomic_load(hr + hfbase + kc * 256,     __ATOMIC_RELAXED, __HIP_MEMORY_SCOPE_AGENT);
        u.q[1] = __hip_atomic_load(hr + hfbase + kc * 256 + 1, __ATOMIC_RELAXED, __HIP_MEMORY_SCOPE_AGENT);
        acc = __builtin_amdgcn_mfma_f32_16x16x32_bf16(u.s, vfr[kc], acc, 0, 0, 0);
      }
    }

    // ---- stage x(t+1): cvt + swizzled LDS write (overlaps MFMA latency) ----
    if (t + 1 < TT) {
#pragma unroll
      for (int r = 0; r < 8; ++r) {
        const int b = r * 4 + bb0;
        const int byte = b * 1024 + kk * 2;
        uint2 p; p.x = pk2(xr[r].x, xr[r].y); p.y = pk2(xr[r].z, xr[r].w);
        *(uint2*)(lds_x + (byte ^ ((b & 7) << 4))) = p;
      }
    }

    // ---- D-frag -> gates LDS ----
#pragma unroll
    for (int r = 0; r < 4; ++r)
      gates[gt][mt * 16 + (lane >> 4) * 4 + r][ln] = acc[r];

    __syncthreads();   // B: gates ready, x staged

    // ---- elementwise LSTM cell (waves 0-3) ----
    if (tid < 256) {
      const float z00 = gates[0][eb][ej]     + bia[0][0];
      const float z01 = gates[0][eb][ej + 1] + bia[0][1];
      const float z10 = gates[1][eb][ej]     + bia[1][0];
      const float z11 = gates[1][eb][ej + 1] + bia[1][1];
      const float z20 = gates[2][eb][ej]     + bia[2][0];
      const float z21 = gates[2][eb][ej + 1] + bia[2][1];
      const float z30 = gates[3][eb][ej]     + bia[3][0];
      const float z31 = gates[3][eb][ej + 1] + bia[3][1];
      const float i0 = sigm(z00), i1 = sigm(z01);
      const float f0 = sigm(z10), f1 = sigm(z11);
      const float g0 = tanh_fast(z20), g1 = tanh_fast(z21);
      const float o0 = sigm(z30), o1 = sigm(z31);
      c0 = f0 * c0 + i0 * g0;
      c1 = f1 * c1 + i1 * g1;
      const float h0 = o0 * tanh_fast(c0);
      const float h1 = o1 * tanh_fast(c1);

      *(float2*)(out + ((size_t)eb * TT + t) * HH + j0 + ej) = make_float2(h0, h1);

      // h store in frag order: row=eb, col=j0+ej
      const int col = j0 + ej;
      const int kc = col >> 5, hi = (col >> 3) & 3, ii = col & 7;
      const int F  = (kc * 2 + (eb >> 4)) * 64 + hi * 16 + (eb & 15);
      unsigned* hw = (unsigned*)(hbuf + (size_t)(t & 1) * 4096);
      __hip_atomic_store(hw + F * 4 + (ii >> 1), pk2(h0, h1),
                         __ATOMIC_RELAXED, __HIP_MEMORY_SCOPE_AGENT);

      if (t == TT - 1) {
        out[(size_t)HS + eb * HH + j0 + ej]               = h0;
        out[(size_t)HS + eb * HH + j0 + ej + 1]           = h1;
        out[(size_t)HS + BB * HH + eb * HH + j0 + ej]     = c0;
        out[(size_t)HS + BB * HH + eb * HH + j0 + ej + 1] = c1;
      }
    }

    __syncthreads();   // C: all waves' h stores vmcnt-drained to LLC

    // publish arrival ASAP (relaxed: no L2 writeback; ordering via sync C)
    if (tid == 0 && t + 1 < TT)
      __hip_atomic_store(&flags[wg], (unsigned)(t + 1),
                         __ATOMIC_RELAXED, __HIP_MEMORY_SCOPE_AGENT);

    // ---- accn = x(t+1)*U from LDS (off the flag-publish critical path;
    //      lds_x not overwritten until after next step's sync A) ----
    if (t + 1 < TT) {
      floatx4 an = {0.f, 0.f, 0.f, 0.f};
#pragma unroll
      for (int kc = 0; kc < 16; ++kc) {
        const short8 xf = *(const short8*)(lds_x + ((xfbase + kc * 64) ^ xfswz));
        an = __builtin_amdgcn_mfma_f32_16x16x32_bf16(xf, ufr[kc], an, 0, 0, 0);
      }
      accn = an;
    }
  }
}

extern "C" void kernel_launch(void* const* d_in, const int* in_sizes, int n_in,
                              void* d_out, int out_size, void* d_ws, size_t ws_size,
                              hipStream_t stream) {
  (void)in_sizes; (void)n_in; (void)out_size; (void)ws_size;
  const float* x  = (const float*)d_in[0];
  const float* Ui = (const float*)d_in[1];
  const float* Vi = (const float*)d_in[2];
  const float* bi = (const float*)d_in[3];
  const float* Uf = (const float*)d_in[4];
  const float* Vf = (const float*)d_in[5];
  const float* bf = (const float*)d_in[6];
  const float* Uc = (const float*)d_in[7];
  const float* Vc = (const float*)d_in[8];
  const float* bc = (const float*)d_in[9];
  const float* Uo = (const float*)d_in[10];
  const float* Vo = (const float*)d_in[11];
  const float* bo = (const float*)d_in[12];

  unsigned long long* hbuf = (unsigned long long*)d_ws;          // 2 x 32KB frag-order h
  unsigned* flags = (unsigned*)((char*)d_ws + 65536);            // 32 packed flags

  hipMemsetAsync(d_ws, 0, 65536 + 256, stream);

  lstm_kernel<<<dim3(NWG), dim3(512), 0, stream>>>(
      x, Ui, Vi, bi, Uf, Vf, bf, Uc, Vc, bc, Uo, Vo, bo,
      (float*)d_out, hbuf, flags);
}

// Round 4
// 10719.982 us; speedup vs baseline: 3.1134x; 1.2584x over previous
//
#include <hip/hip_runtime.h>

// CustomLSTM  B=32, T=2048, H=512  (fp32 in/out)
// 32 persistent WGs x 512 thr. Each WG owns 16 hidden columns (4 gates).
// Batch split into halves P (rows 0-15) / Q (rows 16-31): two independent
// recurrence chains, phase-interleaved so each half's inter-WG exchange
// (LLC flag publish/confirm + h prefetch) hides under the other's compute.
// Weights bf16 in VGPRs, K-split across wave pairs (8 waves = 2 K-halves x 4 gates).

#define BB 32
#define TT 2048
#define HH 512
#define NWG 32
#define HS (BB*TT*HH)

typedef short short8 __attribute__((ext_vector_type(8)));
typedef float floatx4 __attribute__((ext_vector_type(4)));

__device__ __forceinline__ unsigned short f2bf(float f) {
  union { float f; unsigned u; } v; v.f = f;
  return (unsigned short)((v.u + 0x7FFFu + ((v.u >> 16) & 1u)) >> 16);
}
__device__ __forceinline__ unsigned pk2(float a, float b) {
  return (unsigned)f2bf(a) | ((unsigned)f2bf(b) << 16);
}
__device__ __forceinline__ float sigm(float z) { return 1.0f / (1.0f + __expf(-z)); }
__device__ __forceinline__ float tanh_fast(float z) { return 1.0f - 2.0f / (__expf(2.0f * z) + 1.0f); }

#define LOADF(IDX) __hip_atomic_load(&flags[(IDX)], __ATOMIC_RELAXED, __HIP_MEMORY_SCOPE_AGENT)

// load x(TSTEP) rows HALFBASE..+15 into XR (waves 2-7: 384 thr x up-to-6 float4)
#define LOAD_X(XR, HALFBASE, TSTEP)                                              \
    if (tid >= 128) {                                                            \
      _Pragma("unroll")                                                          \
      for (int rr = 0; rr < 6; ++rr) {                                           \
        const int i = rr * 384 + sx;                                             \
        if (i < 2048) {                                                          \
          const int grow = (HALFBASE) + (i >> 7), c4 = i & 127;                  \
          XR[rr] = *(const float4*)(x + ((size_t)grow * TT + (TSTEP)) * HH + c4 * 4); \
        }                                                                        \
      }                                                                          \
    }

// convert + write XR into swizzled lds_x rows HALFBASE..+15
#define STAGE_X(XR, HALFBASE)                                                    \
    if (tid >= 128) {                                                            \
      _Pragma("unroll")                                                          \
      for (int rr = 0; rr < 6; ++rr) {                                           \
        const int i = rr * 384 + sx;                                             \
        if (i < 2048) {                                                          \
          const int grow = (HALFBASE) + (i >> 7), c4 = i & 127;                  \
          uint2 p; p.x = pk2(XR[rr].x, XR[rr].y); p.y = pk2(XR[rr].z, XR[rr].w); \
          *(uint2*)(lds_x + ((grow * 1024 + c4 * 8) ^ ((grow & 7) << 4))) = p;   \
        }                                                                        \
      }                                                                          \
    }

// elementwise LSTM cell for one batch half (tid<128: r=tid>>3, colpair=tid&7)
#define EW_PHASE(HALF, C0, C1, SLOTPTR)                                          \
    if (tid < 128) {                                                             \
      const int er = tid >> 3, ec = (tid & 7) * 2;                               \
      float zz[4][2];                                                            \
      _Pragma("unroll")                                                          \
      for (int g = 0; g < 4; ++g) {                                              \
        zz[g][0] = gates[0][g][er][ec]     + gates[1][g][er][ec]     + bia[g][0];\
        zz[g][1] = gates[0][g][er][ec + 1] + gates[1][g][er][ec + 1] + bia[g][1];\
      }                                                                          \
      const float i0 = sigm(zz[0][0]), i1 = sigm(zz[0][1]);                      \
      const float f0 = sigm(zz[1][0]), f1 = sigm(zz[1][1]);                      \
      const float g0 = tanh_fast(zz[2][0]), g1 = tanh_fast(zz[2][1]);            \
      const float o0 = sigm(zz[3][0]), o1 = sigm(zz[3][1]);                      \
      C0 = f0 * C0 + i0 * g0;  C1 = f1 * C1 + i1 * g1;                           \
      const float h0 = o0 * tanh_fast(C0), h1 = o1 * tanh_fast(C1);              \
      const int gc = j0 + ec;                                                    \
      *(float2*)(out + ((size_t)((HALF)*16 + er) * TT + t) * HH + gc) =          \
          make_float2(h0, h1);                                                   \
      const int uidx = (((gc >> 5) * 64 + ((gc >> 3) & 3) * 16 + er) * 4) + ((gc & 7) >> 1); \
      __hip_atomic_store((unsigned*)(SLOTPTR) + uidx, pk2(h0, h1),               \
                         __ATOMIC_RELAXED, __HIP_MEMORY_SCOPE_AGENT);            \
      if (t == TT - 1) {                                                         \
        const int b = (HALF)*16 + er;                                            \
        out[(size_t)HS + b * HH + gc]               = h0;                        \
        out[(size_t)HS + b * HH + gc + 1]           = h1;                        \
        out[(size_t)HS + BB * HH + b * HH + gc]     = C0;                        \
        out[(size_t)HS + BB * HH + b * HH + gc + 1] = C1;                        \
      }                                                                          \
    }

__global__ __launch_bounds__(512, 1)
void lstm_kernel(const float* __restrict__ x,
                 const float* __restrict__ Ui, const float* __restrict__ Vi, const float* __restrict__ bi,
                 const float* __restrict__ Uf, const float* __restrict__ Vf, const float* __restrict__ bf,
                 const float* __restrict__ Uc, const float* __restrict__ Vc, const float* __restrict__ bc,
                 const float* __restrict__ Uo, const float* __restrict__ Vo, const float* __restrict__ bo,
                 float* __restrict__ out,
                 unsigned long long* __restrict__ hbuf,  // 4 slots x 2048 ull: [P par0, P par1, Q par0, Q par1]
                 unsigned* __restrict__ flags)           // flagsP[0..31], flagsQ[32..63] (zeroed)
{
  __shared__ __align__(16) unsigned char lds_x[BB * HH * 2];  // x(t) bf16 swizzled, 32 KB
  __shared__ __align__(16) float gates[2][4][16][18];         // [Ksub][gate][row][col+pad]

  const int tid  = threadIdx.x;
  const int wg   = blockIdx.x;
  const int lane = tid & 63;
  const int wid  = tid >> 6;
  const int sub  = wid & 1;            // K half: rows sub*256..+256
  const int gt   = wid >> 1;           // gate 0..3
  const int j0   = wg * 16;
  const int ln   = lane & 15;
  const int hi   = lane >> 4;
  const int sx   = tid - 128;          // x-stage thread index (waves 2-7)

  const int xsw    = (ln & 7) << 4;
  const int xbaseP = ln * 1024 + hi * 16;          // + kc*64, ^ xsw
  const int xbaseQ = (16 + ln) * 1024 + hi * 16;
  const int hfb    = sub * 1024 + lane * 2;        // + kcl*128 (ull idx)

  const float* Ug = (gt == 0) ? Ui : (gt == 1) ? Uf : (gt == 2) ? Uc : Uo;
  const float* Vg = (gt == 0) ? Vi : (gt == 1) ? Vf : (gt == 2) ? Vc : Vo;

  // ---- prologue: persistent bf16 weight frags, K range [sub*256, sub*256+256) ----
  short8 ufr[8], vfr[8];
#pragma unroll
  for (int kcl = 0; kcl < 8; ++kcl) {
    const int kc = sub * 8 + kcl;
    short8 a, b;
#pragma unroll
    for (int i = 0; i < 8; ++i) {
      const int krow = kc * 32 + hi * 8 + i;
      a[i] = (short)f2bf(Ug[(size_t)krow * HH + j0 + ln]);
      b[i] = (short)f2bf(Vg[(size_t)krow * HH + j0 + ln]);
    }
    ufr[kcl] = a; vfr[kcl] = b;
  }

  float bia[4][2];
  float cP0 = 0.f, cP1 = 0.f, cQ0 = 0.f, cQ1 = 0.f;
  if (tid < 128) {
    const int ec = (tid & 7) * 2;
    bia[0][0] = bi[j0 + ec]; bia[0][1] = bi[j0 + ec + 1];
    bia[1][0] = bf[j0 + ec]; bia[1][1] = bf[j0 + ec + 1];
    bia[2][0] = bc[j0 + ec]; bia[2][1] = bc[j0 + ec + 1];
    bia[3][0] = bo[j0 + ec]; bia[3][1] = bo[j0 + ec + 1];
  }

  // ---- stage x(0), all 32 rows ----
#pragma unroll
  for (int rr = 0; rr < 8; ++rr) {
    const int i = rr * 512 + tid;
    const int grow = i >> 7, c4 = i & 127;
    const float4 v = *(const float4*)(x + (size_t)grow * TT * HH + c4 * 4);
    uint2 p; p.x = pk2(v.x, v.y); p.y = pk2(v.z, v.w);
    *(uint2*)(lds_x + ((grow * 1024 + c4 * 8) ^ ((grow & 7) << 4))) = p;
  }
  float4 xa[6], xb[6];
  LOAD_X(xa, 0, 1)                     // x(1) rows 0-15, staged at t=0 phase 2
  __syncthreads();

  union HU { unsigned long long q[2]; short8 s; };
  HU hreg[8];
  unsigned fP = 0, fQ = 0;

  for (int t = 0; t < TT; ++t) {
    const int par = t & 1;
    if (t > 0) fQ = LOADF(32 + (lane & 31));          // pre-sample Q flags
    if (t + 1 < TT) LOAD_X(xb, 16, t + 1)             // x(t+1) rows 16-31

    // ======== phase 1: MFMA half P (hreg = hP(t-1), prefetched last iter) ========
    floatx4 acc = {0.f, 0.f, 0.f, 0.f};
#pragma unroll
    for (int kcl = 0; kcl < 8; ++kcl) {
      const short8 xf = *(const short8*)(lds_x + ((xbaseP + (sub * 8 + kcl) * 64) ^ xsw));
      acc = __builtin_amdgcn_mfma_f32_16x16x32_bf16(xf, ufr[kcl], acc, 0, 0, 0);
    }
    if (t > 0) {
#pragma unroll
      for (int kcl = 0; kcl < 8; ++kcl)
        acc = __builtin_amdgcn_mfma_f32_16x16x32_bf16(hreg[kcl].s, vfr[kcl], acc, 0, 0, 0);
    }
#pragma unroll
    for (int rg = 0; rg < 4; ++rg) gates[sub][gt][hi * 4 + rg][ln] = acc[rg];
    __syncthreads();   // B1

    // confirm Q flags (pre-sampled) + prefetch hQ(t-1); per-wave, no barrier
    if (t > 0) {
      const unsigned tq = (unsigned)t;
      while (!__all((int)(fQ >= tq))) {
        __builtin_amdgcn_s_sleep(1);
        fQ = LOADF(32 + (lane & 31));
      }
      const unsigned long long* hq = hbuf + (size_t)(2 + ((t - 1) & 1)) * 2048;
#pragma unroll
      for (int kcl = 0; kcl < 8; ++kcl) {
        hreg[kcl].q[0] = __hip_atomic_load(hq + hfb + kcl * 128,     __ATOMIC_RELAXED, __HIP_MEMORY_SCOPE_AGENT);
        hreg[kcl].q[1] = __hip_atomic_load(hq + hfb + kcl * 128 + 1, __ATOMIC_RELAXED, __HIP_MEMORY_SCOPE_AGENT);
      }
    }

    EW_PHASE(0, cP0, cP1, hbuf + (size_t)par * 2048)  // ew P + store hP(t)
    if (t + 1 < TT) STAGE_X(xa, 0)                    // stage x(t+1) rows 0-15
    __syncthreads();   // C1: hP stores drained
    if (tid == 0)
      __hip_atomic_store(&flags[wg], (unsigned)(t + 1), __ATOMIC_RELAXED, __HIP_MEMORY_SCOPE_AGENT);

    // ======== phase 3: MFMA half Q (hreg = hQ(t-1)) ========
    acc = (floatx4){0.f, 0.f, 0.f, 0.f};
#pragma unroll
    for (int kcl = 0; kcl < 8; ++kcl) {
      const short8 xf = *(const short8*)(lds_x + ((xbaseQ + (sub * 8 + kcl) * 64) ^ xsw));
      acc = __builtin_amdgcn_mfma_f32_16x16x32_bf16(xf, ufr[kcl], acc, 0, 0, 0);
    }
    if (t > 0) {
#pragma unroll
      for (int kcl = 0; kcl < 8; ++kcl)
        acc = __builtin_amdgcn_mfma_f32_16x16x32_bf16(hreg[kcl].s, vfr[kcl], acc, 0, 0, 0);
    }
    if (t + 1 < TT) fP = LOADF(lane & 31);            // pre-sample P flags (t+1)
#pragma unroll
    for (int rg = 0; rg < 4; ++rg) gates[sub][gt][hi * 4 + rg][ln] = acc[rg];
    __syncthreads();   // B2

    EW_PHASE(1, cQ0, cQ1, hbuf + (size_t)(2 + par) * 2048)  // ew Q + store hQ(t)
    if (t + 1 < TT) STAGE_X(xb, 16)                   // stage x(t+1) rows 16-31
    __syncthreads();   // C2: hQ stores drained
    if (tid == 0)
      __hip_atomic_store(&flags[32 + wg], (unsigned)(t + 1), __ATOMIC_RELAXED, __HIP_MEMORY_SCOPE_AGENT);

    // ======== phase 5: confirm P flags, prefetch hP(t); pre-issue x(t+2) ========
    if (t + 1 < TT) {
      const unsigned tp = (unsigned)(t + 1);
      while (!__all((int)(fP >= tp))) {
        __builtin_amdgcn_s_sleep(1);
        fP = LOADF(lane & 31);
      }
      const unsigned long long* hp = hbuf + (size_t)par * 2048;
#pragma unroll
      for (int kcl = 0; kcl < 8; ++kcl) {
        hreg[kcl].q[0] = __hip_atomic_load(hp + hfb + kcl * 128,     __ATOMIC_RELAXED, __HIP_MEMORY_SCOPE_AGENT);
        hreg[kcl].q[1] = __hip_atomic_load(hp + hfb + kcl * 128 + 1, __ATOMIC_RELAXED, __HIP_MEMORY_SCOPE_AGENT);
      }
      if (t + 2 < TT) LOAD_X(xa, 0, t + 2)            // x(t+2) rows 0-15
    }
  }
}

extern "C" void kernel_launch(void* const* d_in, const int* in_sizes, int n_in,
                              void* d_out, int out_size, void* d_ws, size_t ws_size,
                              hipStream_t stream) {
  (void)in_sizes; (void)n_in; (void)out_size; (void)ws_size;
  const float* x  = (const float*)d_in[0];
  const float* Ui = (const float*)d_in[1];
  const float* Vi = (const float*)d_in[2];
  const float* bi = (const float*)d_in[3];
  const float* Uf = (const float*)d_in[4];
  const float* Vf = (const float*)d_in[5];
  const float* bf = (const float*)d_in[6];
  const float* Uc = (const float*)d_in[7];
  const float* Vc = (const float*)d_in[8];
  const float* bc = (const float*)d_in[9];
  const float* Uo = (const float*)d_in[10];
  const float* Vo = (const float*)d_in[11];
  const float* bo = (const float*)d_in[12];

  unsigned long long* hbuf = (unsigned long long*)d_ws;   // 4 x 16 KB h slots
  unsigned* flags = (unsigned*)((char*)d_ws + 65536);     // 64 flags (P then Q)

  // only flags need zeroing; every h slot is written before first read
  hipMemsetAsync((char*)d_ws + 65536, 0, 256, stream);

  lstm_kernel<<<dim3(NWG), dim3(512), 0, stream>>>(
      x, Ui, Vi, bi, Uf, Vf, bf, Uc, Vc, bc, Uo, Vo, bo,
      (float*)d_out, hbuf, flags);
}